// Round 1
// baseline (951.146 us; speedup 1.0000x reference)
//
#include <hip/hip_runtime.h>

// BinaryConv2d: out = conv2d(x, sign(w), pad=1) + sign(bias)
// x: [32,256,56,56] f32, w: [256,256,3,3] f32, bias: [256] f32, out: [32,256,56,56] f32
//
// Implicit GEMM on MFMA bf16: M = O (256), N = pixels (32*56*56 = 100352),
// K = C*9 = 2304 processed as 9 taps x 8 chunks of 32.
// Weights pre-binarized to bf16 Wt[tap][o][c] in workspace (1.13 MB).

#define N_IMG 32
#define C_IN  256
#define H_IN  56
#define W_IN  56
#define O_OUT 256
#define HW    (H_IN * W_IN)      // 3136
#define CHW   (C_IN * HW)        // 802816
#define K_RAW (C_IN * 9)         // 2304 (weight o-stride)

#define PIX_TILE 128
#define O_TILE   128
#define KC       32              // K elements per step
#define PITCH    40              // bf16 elems per LDS row (80B: 16B-aligned, non-pow2 banks)

typedef __bf16 bf16x8 __attribute__((ext_vector_type(8)));
typedef float  f32x4  __attribute__((ext_vector_type(4)));

#define WT_ELEMS (9 * O_OUT * C_IN)     // 589824
#define WT_BYTES (WT_ELEMS * 2)         // 1179648

// ---- weight binarize + transpose: wt[(tap*256 + o)*256 + c] = sign(w[o,c,tap]) ----
__global__ void wtrans_kernel(const float* __restrict__ w, __bf16* __restrict__ wt) {
    int idx = blockIdx.x * 256 + threadIdx.x;     // 0 .. 589823
    int c    = idx & 255;
    int rest = idx >> 8;
    int o    = rest & 255;
    int tap  = rest >> 8;                          // 0..8
    float v = w[o * K_RAW + c * 9 + tap];
    wt[idx] = (v >= 0.0f) ? (__bf16)1.0f : (__bf16)(-1.0f);
}

// ---- main: block computes 128 o x 128 pixels ----
template <bool USE_WT>
__launch_bounds__(256, 2)
__global__ void bconv_kernel(const float* __restrict__ x,
                             const float* __restrict__ w,       // raw fp32 (fallback)
                             const __bf16* __restrict__ wt,     // [9][256][256] bf16
                             const float* __restrict__ bias,
                             float* __restrict__ out) {
    __shared__ __attribute__((aligned(16))) __bf16 As[O_TILE * PITCH];   // [o][k]
    __shared__ __attribute__((aligned(16))) __bf16 Bs[PIX_TILE * PITCH]; // [pix][k]

    const int tid  = threadIdx.x;
    const int lane = tid & 63;
    const int wv   = tid >> 6;
    const int pblk = blockIdx.x;      // 0..783
    const int oblk = blockIdx.y;      // 0..1

    // ---- B-staging thread mapping: 128 pixels x 2 c-groups of 16 ----
    const int p_local = tid & 127;
    const int cgrp    = tid >> 7;     // 0 or 1
    const int pixel   = pblk * PIX_TILE + p_local;
    const int n_img   = pixel / HW;
    const int hw      = pixel - n_img * HW;
    const int h       = hw / W_IN;
    const int wx      = hw - h * W_IN;
    const float* xbase = x + (size_t)n_img * CHW;

    f32x4 acc[8][2];
#pragma unroll
    for (int mt = 0; mt < 8; ++mt)
#pragma unroll
        for (int nt = 0; nt < 2; ++nt)
            acc[mt][nt] = (f32x4){0.f, 0.f, 0.f, 0.f};

    const int pix_wave = wv * 32;     // wave's pixel offset within tile
    const int row  = lane & 15;
    const int quad = lane >> 4;

    for (int tap = 0; tap < 9; ++tap) {
        const int dh = tap / 3 - 1;
        const int dw = tap % 3 - 1;
        const int hh = h + dh;
        const int ww = wx + dw;
        const bool valid = ((unsigned)hh < (unsigned)H_IN) && ((unsigned)ww < (unsigned)W_IN);
        const int offs = hh * W_IN + ww;    // only dereferenced when valid

        for (int cc = 0; cc < 8; ++cc) {
            __syncthreads();
            // ---- stage A: binarized weights [128 o][32 c] ----
            if (USE_WT) {
                const __bf16* wsrc = wt + ((size_t)(tap * O_OUT + oblk * O_TILE) * C_IN) + cc * KC;
#pragma unroll
                for (int rep = 0; rep < 2; ++rep) {
                    int v  = tid + rep * 256;        // 0..511
                    int oa = v >> 2;                 // 0..127
                    int c8 = v & 3;                  // 0..3
                    bf16x8 val = *(const bf16x8*)(wsrc + oa * C_IN + c8 * 8);
                    *(bf16x8*)(&As[oa * PITCH + c8 * 8]) = val;
                }
            } else {
#pragma unroll
                for (int rep = 0; rep < 2; ++rep) {
                    int v  = tid + rep * 256;
                    int oa = v >> 2;
                    int c8 = v & 3;
                    const float* wsrc = w + (size_t)(oblk * O_TILE + oa) * K_RAW
                                          + (cc * KC + c8 * 8) * 9 + tap;
                    bf16x8 val;
#pragma unroll
                    for (int j = 0; j < 8; ++j)
                        val[j] = (wsrc[j * 9] >= 0.0f) ? (__bf16)1.0f : (__bf16)(-1.0f);
                    *(bf16x8*)(&As[oa * PITCH + c8 * 8]) = val;
                }
            }
            // ---- stage B: im2col(x) [128 pix][32 c], fp32 -> bf16 ----
            {
                const int cbase = (cc * KC + cgrp * 16) * HW + offs;
#pragma unroll
                for (int g = 0; g < 2; ++g) {
                    bf16x8 vb;
#pragma unroll
                    for (int j = 0; j < 8; ++j) {
                        float f = valid ? xbase[cbase + (g * 8 + j) * HW] : 0.0f;
                        vb[j] = (__bf16)f;
                    }
                    *(bf16x8*)(&Bs[p_local * PITCH + cgrp * 16 + g * 8]) = vb;
                }
            }
            __syncthreads();
            // ---- compute: 16 MFMA per wave ----
            bf16x8 bfrag[2];
#pragma unroll
            for (int nt = 0; nt < 2; ++nt)
                bfrag[nt] = *(const bf16x8*)(&Bs[(pix_wave + nt * 16 + row) * PITCH + quad * 8]);
#pragma unroll
            for (int mt = 0; mt < 8; ++mt) {
                bf16x8 afrag = *(const bf16x8*)(&As[(mt * 16 + row) * PITCH + quad * 8]);
#pragma unroll
                for (int nt = 0; nt < 2; ++nt)
                    acc[mt][nt] = __builtin_amdgcn_mfma_f32_16x16x32_bf16(
                        afrag, bfrag[nt], acc[mt][nt], 0, 0, 0);
            }
        }
    }

    // ---- epilogue: D[o][pix], o = mt*16 + quad*4 + r, pix = pix_wave + nt*16 + row ----
#pragma unroll
    for (int nt = 0; nt < 2; ++nt) {
        int pix = pblk * PIX_TILE + pix_wave + nt * 16 + row;
        int ni  = pix / HW;
        int phw = pix - ni * HW;
        float* obase = out + (size_t)ni * (O_OUT * HW) + phw;
#pragma unroll
        for (int mt = 0; mt < 8; ++mt) {
            int o0 = oblk * O_TILE + mt * 16 + quad * 4;
#pragma unroll
            for (int r = 0; r < 4; ++r) {
                int o = o0 + r;
                float sb = (bias[o] >= 0.0f) ? 1.0f : -1.0f;
                obase[(size_t)o * HW] = acc[mt][nt][r] + sb;
            }
        }
    }
}

extern "C" void kernel_launch(void* const* d_in, const int* in_sizes, int n_in,
                              void* d_out, int out_size, void* d_ws, size_t ws_size,
                              hipStream_t stream) {
    const float* x    = (const float*)d_in[0];
    const float* w    = (const float*)d_in[1];
    const float* bias = (const float*)d_in[2];
    float* out        = (float*)d_out;

    const int pix_blocks = (N_IMG * HW) / PIX_TILE;   // 784
    dim3 grid(pix_blocks, O_OUT / O_TILE, 1);         // 784 x 2
    dim3 block(256, 1, 1);

    if (ws_size >= (size_t)WT_BYTES) {
        __bf16* wt = (__bf16*)d_ws;
        wtrans_kernel<<<WT_ELEMS / 256, 256, 0, stream>>>(w, wt);
        bconv_kernel<true><<<grid, block, 0, stream>>>(x, w, wt, bias, out);
    } else {
        bconv_kernel<false><<<grid, block, 0, stream>>>(x, w, (const __bf16*)nullptr, bias, out);
    }
}

// Round 2
// 366.907 us; speedup vs baseline: 2.5923x; 2.5923x over previous
//
#include <hip/hip_runtime.h>

// BinaryConv2d: out = conv2d(x, sign(w), pad=1) + sign(bias)
// x: [32,256,56,56] f32, w: [256,256,3,3] f32, bias: [256] f32, out: [32,256,56,56] f32
//
// Round 2: halo-reuse implicit GEMM.
//  - xtrans: x NCHW f32 -> xt[n][cc(8)][hh(58)][ww(58)][c(32)] bf16, zero border.
//  - wtrans: w -> wt[tap(9)][o(256)][c(256)] bf16 in {-1,+1}.
//  - bconv2: per block 128 o x 112 pixels (2 rows x 56). Per K-chunk (32 ch):
//      stage 4x58x32 halo once, reuse across 9 taps (16 MFMA/wave per tap).

#define N_IMG 32
#define C_IN  256
#define H_IN  56
#define W_IN  56
#define O_OUT 256
#define HW    (H_IN * W_IN)      // 3136
#define K_RAW (C_IN * 9)         // 2304 (weight o-stride in raw w)

#define PITCH   40               // bf16 elems per LDS row (80 B: 16B-aligned, 20-bank stride)
#define BS_ROW  (58 * PITCH)     // 2320 elems per halo row
#define XT_HSTR (58 * 32)        // 1856 elems per xt padded row
#define XT_CSTR (58 * 58 * 32)   // elems per (n,cc) plane: 107648

typedef __bf16 bf16x8 __attribute__((ext_vector_type(8)));
typedef float  f32x4  __attribute__((ext_vector_type(4)));

#define WT_ELEMS (9 * O_OUT * C_IN)                 // 589824
#define WT_BYTES (WT_ELEMS * 2)                     // 1179648
#define XT_ELEMS ((size_t)N_IMG * 8 * 58 * 58 * 32) // 27557888
#define XT_BYTES (XT_ELEMS * 2)                     // 55115776
#define WS_NEED  (XT_BYTES + WT_BYTES)              // 56295424

// ---- weight binarize + transpose: wt[(tap*256 + o)*256 + c] = sign(w[o,c,tap]) ----
__global__ void wtrans_kernel(const float* __restrict__ w, __bf16* __restrict__ wt) {
    int idx = blockIdx.x * 256 + threadIdx.x;     // 0 .. 589823
    int c    = idx & 255;
    int rest = idx >> 8;
    int o    = rest & 255;
    int tap  = rest >> 8;                          // 0..8
    float v = w[o * K_RAW + c * 9 + tap];
    wt[idx] = (v >= 0.0f) ? (__bf16)1.0f : (__bf16)(-1.0f);
}

// ---- x transpose: NCHW f32 -> [n][cc][hh][ww][c32] bf16, zero-padded border ----
__global__ void xtrans_kernel(const float* __restrict__ x, __bf16* __restrict__ xt) {
    const int hh = blockIdx.x;         // 0..57
    const int cc = blockIdx.y;         // 0..7
    const int n  = blockIdx.z;         // 0..31
    const int ww = threadIdx.x;        // 0..63 (valid < 58)
    const int cy = threadIdx.y;        // 0..3 (8 channels each)
    if (ww >= 58) return;

    bf16x8 v = (bf16x8){0, 0, 0, 0, 0, 0, 0, 0};
    if (hh >= 1 && hh <= 56 && ww >= 1 && ww <= 56) {
        const float* src = x + ((size_t)n * C_IN + cc * 32 + cy * 8) * HW
                             + (hh - 1) * W_IN + (ww - 1);
#pragma unroll
        for (int j = 0; j < 8; ++j)
            v[j] = (__bf16)src[(size_t)j * HW];
    }
    __bf16* dst = xt + (((size_t)(n * 8 + cc) * 58 + hh) * 58 + ww) * 32 + cy * 8;
    *(bf16x8*)dst = v;
}

// ---- main: block = 128 o x 112 pixels (2 out rows x 56 cols), 9-tap halo reuse ----
__launch_bounds__(256, 2)
__global__ void bconv2_kernel(const __bf16* __restrict__ xt,
                              const __bf16* __restrict__ wt,
                              const float* __restrict__ bias,
                              float* __restrict__ out) {
    __shared__ __attribute__((aligned(16))) __bf16 Bs[4 * BS_ROW];    // 18560 B halo
    __shared__ __attribute__((aligned(16))) __bf16 As[128 * PITCH];   // 10240 B weights

    const int tid  = threadIdx.x;
    const int lane = tid & 63;
    const int wv   = tid >> 6;
    const int row  = lane & 15;
    const int quad = lane >> 4;

    const int nrp  = blockIdx.x;              // 0..895
    const int n    = nrp / 28;
    const int rp   = nrp - n * 28;
    const int oblk = blockIdx.y;              // 0..1
    const int h0   = rp * 2;                  // first output row of tile

    // per-lane output pixel coords (nt = 0,1), p in [0,128), live if p < 112
    int pr[2], pc[2];
    bool live[2];
#pragma unroll
    for (int nt = 0; nt < 2; ++nt) {
        int p = wv * 32 + nt * 16 + row;
        live[nt] = (p < 112);
        int r = p / 56;
        int c = p - r * 56;
        if (!live[nt]) { r = 0; c = 0; }
        pr[nt] = r;
        pc[nt] = c;
    }

    f32x4 acc[8][2];
#pragma unroll
    for (int mt = 0; mt < 8; ++mt)
#pragma unroll
        for (int nt = 0; nt < 2; ++nt)
            acc[mt][nt] = (f32x4){0.f, 0.f, 0.f, 0.f};

    for (int cc = 0; cc < 8; ++cc) {
        // ---- stage B halo: 4 rows x 58 cols x 32 ch, each row 3712 B contiguous ----
        const __bf16* bsrc = xt + ((size_t)(n * 8 + cc) * 58 + h0) * XT_HSTR / 32 * 32; // = ((n*8+cc)*58+h0)*1856
        // (expression kept simple below)
        const __bf16* bsrc2 = xt + ((size_t)(n * 8 + cc) * 58 + h0) * (size_t)XT_HSTR / 58; // avoid: recompute cleanly
        (void)bsrc; (void)bsrc2;
        const __bf16* bbase = xt + (size_t)(n * 8 + cc) * XT_CSTR + (size_t)h0 * XT_HSTR;

        __syncthreads();   // protect Bs overwrite vs previous cc's reads
        if (tid < 232) {
            int col = tid >> 2;          // 0..57
            int cg  = tid & 3;           // 0..3
#pragma unroll
            for (int r4 = 0; r4 < 4; ++r4) {
                bf16x8 v = *(const bf16x8*)(bbase + r4 * XT_HSTR + tid * 8);
                *(bf16x8*)(&Bs[r4 * BS_ROW + col * PITCH + cg * 8]) = v;
            }
        }

        for (int tap = 0; tap < 9; ++tap) {
            __syncthreads();   // Bs writes -> reads (tap 0); As overwrite vs prev tap reads
            // ---- stage A: 128 o x 32 ch for (tap, cc); rows 64 B at stride 512 B ----
            const __bf16* asrc = wt + ((size_t)(tap * O_OUT + oblk * 128) * C_IN) + cc * 32;
#pragma unroll
            for (int it = 0; it < 2; ++it) {
                int idx = tid + it * 256;    // 0..511
                int o   = idx >> 2;
                int cg  = idx & 3;
                *(bf16x8*)(&As[o * PITCH + cg * 8]) =
                    *(const bf16x8*)(asrc + o * C_IN + cg * 8);
            }
            __syncthreads();

            const int dh = tap / 3;      // 0..2 (halo row offset)
            const int dw = tap - dh * 3; // 0..2 (halo col offset)

            bf16x8 bfrag[2];
#pragma unroll
            for (int nt = 0; nt < 2; ++nt)
                bfrag[nt] = *(const bf16x8*)(
                    &Bs[(pr[nt] + dh) * BS_ROW + (pc[nt] + dw) * PITCH + quad * 8]);
#pragma unroll
            for (int mt = 0; mt < 8; ++mt) {
                bf16x8 afrag = *(const bf16x8*)(&As[(mt * 16 + row) * PITCH + quad * 8]);
#pragma unroll
                for (int nt = 0; nt < 2; ++nt)
                    acc[mt][nt] = __builtin_amdgcn_mfma_f32_16x16x32_bf16(
                        afrag, bfrag[nt], acc[mt][nt], 0, 0, 0);
            }
        }
    }

    // ---- epilogue: o = oblk*128 + mt*16 + quad*4 + r; pix row/col from pr/pc ----
#pragma unroll
    for (int nt = 0; nt < 2; ++nt) {
        if (!live[nt]) continue;
        float* obase = out + ((size_t)n * O_OUT + oblk * 128) * HW
                           + (h0 + pr[nt]) * W_IN + pc[nt];
#pragma unroll
        for (int mt = 0; mt < 8; ++mt) {
#pragma unroll
            for (int r = 0; r < 4; ++r) {
                int ol = mt * 16 + quad * 4 + r;
                float sb = (bias[oblk * 128 + ol] >= 0.0f) ? 1.0f : -1.0f;
                obase[(size_t)ol * HW] = acc[mt][nt][r] + sb;
            }
        }
    }
}

// ================= Round-1 fallback (used only if ws too small) =================
#define PIX_TILE 128
#define O_TILE   128
#define KC       32
#define CHW      (C_IN * HW)

template <bool USE_WT>
__launch_bounds__(256, 2)
__global__ void bconv_kernel(const float* __restrict__ x,
                             const float* __restrict__ w,
                             const __bf16* __restrict__ wt,
                             const float* __restrict__ bias,
                             float* __restrict__ out) {
    __shared__ __attribute__((aligned(16))) __bf16 Asf[O_TILE * PITCH];
    __shared__ __attribute__((aligned(16))) __bf16 Bsf[PIX_TILE * PITCH];

    const int tid  = threadIdx.x;
    const int lane = tid & 63;
    const int wv   = tid >> 6;
    const int pblk = blockIdx.x;
    const int oblk = blockIdx.y;

    const int p_local = tid & 127;
    const int cgrp    = tid >> 7;
    const int pixel   = pblk * PIX_TILE + p_local;
    const int n_img   = pixel / HW;
    const int hw      = pixel - n_img * HW;
    const int h       = hw / W_IN;
    const int wx      = hw - h * W_IN;
    const float* xbase = x + (size_t)n_img * CHW;

    f32x4 acc[8][2];
#pragma unroll
    for (int mt = 0; mt < 8; ++mt)
#pragma unroll
        for (int nt = 0; nt < 2; ++nt)
            acc[mt][nt] = (f32x4){0.f, 0.f, 0.f, 0.f};

    const int pix_wave = wv * 32;
    const int row  = lane & 15;
    const int quad = lane >> 4;

    for (int tap = 0; tap < 9; ++tap) {
        const int dh = tap / 3 - 1;
        const int dw = tap % 3 - 1;
        const int hh = h + dh;
        const int ww = wx + dw;
        const bool valid = ((unsigned)hh < (unsigned)H_IN) && ((unsigned)ww < (unsigned)W_IN);
        const int offs = hh * W_IN + ww;

        for (int ck = 0; ck < 8; ++ck) {
            __syncthreads();
            if (USE_WT) {
                const __bf16* wsrc = wt + ((size_t)(tap * O_OUT + oblk * O_TILE) * C_IN) + ck * KC;
#pragma unroll
                for (int rep = 0; rep < 2; ++rep) {
                    int v  = tid + rep * 256;
                    int oa = v >> 2;
                    int c8 = v & 3;
                    bf16x8 val = *(const bf16x8*)(wsrc + oa * C_IN + c8 * 8);
                    *(bf16x8*)(&Asf[oa * PITCH + c8 * 8]) = val;
                }
            } else {
#pragma unroll
                for (int rep = 0; rep < 2; ++rep) {
                    int v  = tid + rep * 256;
                    int oa = v >> 2;
                    int c8 = v & 3;
                    const float* wsrc = w + (size_t)(oblk * O_TILE + oa) * K_RAW
                                          + (ck * KC + c8 * 8) * 9 + tap;
                    bf16x8 val;
#pragma unroll
                    for (int j = 0; j < 8; ++j)
                        val[j] = (wsrc[j * 9] >= 0.0f) ? (__bf16)1.0f : (__bf16)(-1.0f);
                    *(bf16x8*)(&Asf[oa * PITCH + c8 * 8]) = val;
                }
            }
            {
                const int cbase = (ck * KC + cgrp * 16) * HW + offs;
#pragma unroll
                for (int g = 0; g < 2; ++g) {
                    bf16x8 vb;
#pragma unroll
                    for (int j = 0; j < 8; ++j) {
                        float f = valid ? xbase[cbase + (g * 8 + j) * HW] : 0.0f;
                        vb[j] = (__bf16)f;
                    }
                    *(bf16x8*)(&Bsf[p_local * PITCH + cgrp * 16 + g * 8]) = vb;
                }
            }
            __syncthreads();
            bf16x8 bfrag[2];
#pragma unroll
            for (int nt = 0; nt < 2; ++nt)
                bfrag[nt] = *(const bf16x8*)(&Bsf[(pix_wave + nt * 16 + row) * PITCH + quad * 8]);
#pragma unroll
            for (int mt = 0; mt < 8; ++mt) {
                bf16x8 afrag = *(const bf16x8*)(&Asf[(mt * 16 + row) * PITCH + quad * 8]);
#pragma unroll
                for (int nt = 0; nt < 2; ++nt)
                    acc[mt][nt] = __builtin_amdgcn_mfma_f32_16x16x32_bf16(
                        afrag, bfrag[nt], acc[mt][nt], 0, 0, 0);
            }
        }
    }

#pragma unroll
    for (int nt = 0; nt < 2; ++nt) {
        int pix = pblk * PIX_TILE + pix_wave + nt * 16 + row;
        int ni  = pix / HW;
        int phw = pix - ni * HW;
        float* obase = out + (size_t)ni * (O_OUT * HW) + phw;
#pragma unroll
        for (int mt = 0; mt < 8; ++mt) {
            int o0 = oblk * O_TILE + mt * 16 + quad * 4;
#pragma unroll
            for (int r = 0; r < 4; ++r) {
                int o = o0 + r;
                float sb = (bias[o] >= 0.0f) ? 1.0f : -1.0f;
                obase[(size_t)o * HW] = acc[mt][nt][r] + sb;
            }
        }
    }
}

extern "C" void kernel_launch(void* const* d_in, const int* in_sizes, int n_in,
                              void* d_out, int out_size, void* d_ws, size_t ws_size,
                              hipStream_t stream) {
    const float* x    = (const float*)d_in[0];
    const float* w    = (const float*)d_in[1];
    const float* bias = (const float*)d_in[2];
    float* out        = (float*)d_out;

    if (ws_size >= (size_t)WS_NEED) {
        __bf16* xt = (__bf16*)d_ws;
        __bf16* wt = (__bf16*)((char*)d_ws + XT_BYTES);
        xtrans_kernel<<<dim3(58, 8, N_IMG), dim3(64, 4), 0, stream>>>(x, xt);
        wtrans_kernel<<<WT_ELEMS / 256, 256, 0, stream>>>(w, wt);
        bconv2_kernel<<<dim3(N_IMG * 28, 2), dim3(256), 0, stream>>>(xt, wt, bias, out);
    } else if (ws_size >= (size_t)WT_BYTES) {
        __bf16* wt = (__bf16*)d_ws;
        wtrans_kernel<<<WT_ELEMS / 256, 256, 0, stream>>>(w, wt);
        bconv_kernel<true><<<dim3((N_IMG * HW) / PIX_TILE, 2), dim3(256), 0, stream>>>(
            x, w, wt, bias, out);
    } else {
        bconv_kernel<false><<<dim3((N_IMG * HW) / PIX_TILE, 2), dim3(256), 0, stream>>>(
            x, w, (const __bf16*)nullptr, bias, out);
    }
}

// Round 3
// 342.628 us; speedup vs baseline: 2.7760x; 1.0709x over previous
//
#include <hip/hip_runtime.h>

// BinaryConv2d: out = conv2d(x, sign(w), pad=1) + sign(bias)
// x: [32,256,56,56] f32, w: [256,256,3,3] f32, bias: [256] f32, out: [32,256,56,56] f32
//
// Round 3:
//  - xtrans: store-coalesced layout transform (each wave stores 1024 B contiguous).
//  - bconv2: 128 o x 224 px (4 rows x 56) per block, nt=4 per wave (32 MFMA / 12 LDS
//    reads per tap), A-tile double-buffered in LDS (1 sync/tap, staging overlaps MFMA).

#define N_IMG 32
#define C_IN  256
#define H_IN  56
#define W_IN  56
#define O_OUT 256
#define HW    (H_IN * W_IN)      // 3136
#define K_RAW (C_IN * 9)         // 2304 (weight o-stride in raw w)

#define PITCH   40               // bf16 elems per LDS row (80 B: 16B-aligned, 20-bank stride)
#define BS_ROW  (58 * PITCH)     // 2320 elems per halo row
#define XT_HSTR (58 * 32)        // 1856 elems per xt padded row
#define XT_CSTR (58 * 58 * 32)   // 107648 elems per (n,cc) plane

typedef __bf16 bf16x8 __attribute__((ext_vector_type(8)));
typedef float  f32x4  __attribute__((ext_vector_type(4)));

#define WT_ELEMS (9 * O_OUT * C_IN)                 // 589824
#define WT_BYTES (WT_ELEMS * 2)                     // 1179648
#define XT_ELEMS ((size_t)N_IMG * 8 * 58 * 58 * 32) // 27557888
#define XT_BYTES (XT_ELEMS * 2)                     // 55115776
#define WS_NEED  (XT_BYTES + WT_BYTES)              // 56295424

// ---- weight binarize + transpose: wt[(tap*256 + o)*256 + c] = sign(w[o,c,tap]) ----
__global__ void wtrans_kernel(const float* __restrict__ w, __bf16* __restrict__ wt) {
    int idx = blockIdx.x * 256 + threadIdx.x;     // 0 .. 589823
    int c    = idx & 255;
    int rest = idx >> 8;
    int o    = rest & 255;
    int tap  = rest >> 8;                          // 0..8
    float v = w[o * K_RAW + c * 9 + tap];
    wt[idx] = (v >= 0.0f) ? (__bf16)1.0f : (__bf16)(-1.0f);
}

// ---- x transpose: NCHW f32 -> [n][cc][hh][ww][c32] bf16, zero-padded border ----
// Thread map: ww = t>>2, cy = t&3 -> each wave stores 1024 B contiguous; each load
// instr reads 4 channel-planes x 64 B fully-used lines.
__global__ void xtrans_kernel(const float* __restrict__ x, __bf16* __restrict__ xt) {
    const int hh = blockIdx.x;         // 0..57
    const int cc = blockIdx.y;         // 0..7
    const int n  = blockIdx.z;         // 0..31
    const int t  = threadIdx.x;
    const int ww = t >> 2;             // 0..63 (valid < 58)
    const int cy = t & 3;              // 8 channels each
    if (ww >= 58) return;

    bf16x8 v = (bf16x8){0, 0, 0, 0, 0, 0, 0, 0};
    if (hh >= 1 && hh <= 56 && ww >= 1 && ww <= 56) {
        const float* src = x + ((size_t)n * C_IN + cc * 32 + cy * 8) * HW
                             + (hh - 1) * W_IN + (ww - 1);
#pragma unroll
        for (int j = 0; j < 8; ++j)
            v[j] = (__bf16)src[(size_t)j * HW];
    }
    __bf16* dst = xt + (((size_t)(n * 8 + cc) * 58 + hh) * 58 + ww) * 32 + cy * 8;
    *(bf16x8*)dst = v;
}

// ---- main: block = 128 o x 224 pixels (4 out rows x 56 cols), 9-tap halo reuse ----
__launch_bounds__(256, 2)
__global__ void bconv2_kernel(const __bf16* __restrict__ xt,
                              const __bf16* __restrict__ wt,
                              const float* __restrict__ bias,
                              float* __restrict__ out) {
    __shared__ __attribute__((aligned(16))) __bf16 Bs[6 * BS_ROW];       // 27840 B halo
    __shared__ __attribute__((aligned(16))) __bf16 As[2][128 * PITCH];   // 2 x 10240 B

    const int tid  = threadIdx.x;
    const int lane = tid & 63;
    const int wv   = tid >> 6;
    const int row  = lane & 15;
    const int quad = lane >> 4;

    const int nrp  = blockIdx.x;              // 0..447
    const int n    = nrp / 14;
    const int rp   = nrp - n * 14;
    const int oblk = blockIdx.y;              // 0..1
    const int h0   = rp * 4;                  // first output row of tile

    // per-lane output pixel coords (nt = 0..3), p in [0,256), live if p < 224
    int pr[4], pc[4];
    bool live[4];
#pragma unroll
    for (int nt = 0; nt < 4; ++nt) {
        int p = wv * 64 + nt * 16 + row;
        live[nt] = (p < 224);
        int r = p / 56;
        int c = p - r * 56;
        if (!live[nt]) { r = 0; c = 0; }
        pr[nt] = r;
        pc[nt] = c;
    }

    f32x4 acc[8][4];
#pragma unroll
    for (int mt = 0; mt < 8; ++mt)
#pragma unroll
        for (int nt = 0; nt < 4; ++nt)
            acc[mt][nt] = (f32x4){0.f, 0.f, 0.f, 0.f};

    // stage A-tile for step stp = cc*9 + tap into buffer buf
    auto stageA = [&](int stp, int buf) {
        int scc  = stp / 9;
        int stap = stp - scc * 9;
        const __bf16* asrc = wt + ((size_t)(stap * O_OUT + oblk * 128) * C_IN) + scc * 32;
#pragma unroll
        for (int it = 0; it < 2; ++it) {
            int idx = tid + it * 256;    // 0..511
            int o   = idx >> 2;
            int cg  = idx & 3;
            *(bf16x8*)(&As[buf][o * PITCH + cg * 8]) =
                *(const bf16x8*)(asrc + o * C_IN + cg * 8);
        }
    };

    stageA(0, 0);   // prologue: (cc=0, tap=0) into buffer 0

    for (int cc = 0; cc < 8; ++cc) {
        __syncthreads();   // prior cc's Bs reads + As[next] reads complete
        // ---- stage B halo: 6 rows x 58 cols x 32 ch (each row 3712 B contiguous) ----
        const __bf16* bbase = xt + (size_t)(n * 8 + cc) * XT_CSTR + (size_t)h0 * XT_HSTR;
        if (tid < 232) {
            const int col = tid >> 2;    // 0..57
            const int cg  = tid & 3;     // 0..3
#pragma unroll
            for (int r6 = 0; r6 < 6; ++r6) {
                bf16x8 v = *(const bf16x8*)(bbase + r6 * XT_HSTR + tid * 8);
                *(bf16x8*)(&Bs[r6 * BS_ROW + col * PITCH + cg * 8]) = v;
            }
        }

        for (int tap = 0; tap < 9; ++tap) {
            const int s = cc * 9 + tap;
            if (tap) __syncthreads();          // As[s&1] staged last step -> visible
            if (s + 1 < 72) stageA(s + 1, (s + 1) & 1);   // overlaps this step's MFMA
            if (!tap) __syncthreads();         // Bs staged this step -> visible

            const int dh = tap / 3;
            const int dw = tap - dh * 3;
            const __bf16* Ab = As[s & 1];

            bf16x8 bfrag[4];
#pragma unroll
            for (int nt = 0; nt < 4; ++nt)
                bfrag[nt] = *(const bf16x8*)(
                    &Bs[(pr[nt] + dh) * BS_ROW + (pc[nt] + dw) * PITCH + quad * 8]);
#pragma unroll
            for (int mt = 0; mt < 8; ++mt) {
                bf16x8 afrag = *(const bf16x8*)(&Ab[(mt * 16 + row) * PITCH + quad * 8]);
#pragma unroll
                for (int nt = 0; nt < 4; ++nt)
                    acc[mt][nt] = __builtin_amdgcn_mfma_f32_16x16x32_bf16(
                        afrag, bfrag[nt], acc[mt][nt], 0, 0, 0);
            }
        }
    }

    // ---- epilogue: o = oblk*128 + mt*16 + quad*4 + r; pix = (h0+pr, pc) ----
#pragma unroll
    for (int nt = 0; nt < 4; ++nt) {
        if (!live[nt]) continue;
        float* obase = out + ((size_t)n * O_OUT + oblk * 128) * HW
                           + (h0 + pr[nt]) * W_IN + pc[nt];
#pragma unroll
        for (int mt = 0; mt < 8; ++mt) {
#pragma unroll
            for (int r = 0; r < 4; ++r) {
                int ol = mt * 16 + quad * 4 + r;
                float sb = (bias[oblk * 128 + ol] >= 0.0f) ? 1.0f : -1.0f;
                obase[(size_t)ol * HW] = acc[mt][nt][r] + sb;
            }
        }
    }
}

// ================= Round-1 fallback (used only if ws too small) =================
#define PIX_TILE 128
#define O_TILE   128
#define KC       32
#define CHW      (C_IN * HW)

template <bool USE_WT>
__launch_bounds__(256, 2)
__global__ void bconv_kernel(const float* __restrict__ x,
                             const float* __restrict__ w,
                             const __bf16* __restrict__ wt,
                             const float* __restrict__ bias,
                             float* __restrict__ out) {
    __shared__ __attribute__((aligned(16))) __bf16 Asf[O_TILE * PITCH];
    __shared__ __attribute__((aligned(16))) __bf16 Bsf[PIX_TILE * PITCH];

    const int tid  = threadIdx.x;
    const int lane = tid & 63;
    const int wv   = tid >> 6;
    const int pblk = blockIdx.x;
    const int oblk = blockIdx.y;

    const int p_local = tid & 127;
    const int cgrp    = tid >> 7;
    const int pixel   = pblk * PIX_TILE + p_local;
    const int n_img   = pixel / HW;
    const int hw      = pixel - n_img * HW;
    const int h       = hw / W_IN;
    const int wx      = hw - h * W_IN;
    const float* xbase = x + (size_t)n_img * CHW;

    f32x4 acc[8][2];
#pragma unroll
    for (int mt = 0; mt < 8; ++mt)
#pragma unroll
        for (int nt = 0; nt < 2; ++nt)
            acc[mt][nt] = (f32x4){0.f, 0.f, 0.f, 0.f};

    const int pix_wave = wv * 32;
    const int row  = lane & 15;
    const int quad = lane >> 4;

    for (int tap = 0; tap < 9; ++tap) {
        const int dh = tap / 3 - 1;
        const int dw = tap % 3 - 1;
        const int hh = h + dh;
        const int ww = wx + dw;
        const bool valid = ((unsigned)hh < (unsigned)H_IN) && ((unsigned)ww < (unsigned)W_IN);
        const int offs = hh * W_IN + ww;

        for (int ck = 0; ck < 8; ++ck) {
            __syncthreads();
            if (USE_WT) {
                const __bf16* wsrc = wt + ((size_t)(tap * O_OUT + oblk * O_TILE) * C_IN) + ck * KC;
#pragma unroll
                for (int rep = 0; rep < 2; ++rep) {
                    int v  = tid + rep * 256;
                    int oa = v >> 2;
                    int c8 = v & 3;
                    bf16x8 val = *(const bf16x8*)(wsrc + oa * C_IN + c8 * 8);
                    *(bf16x8*)(&Asf[oa * PITCH + c8 * 8]) = val;
                }
            } else {
#pragma unroll
                for (int rep = 0; rep < 2; ++rep) {
                    int v  = tid + rep * 256;
                    int oa = v >> 2;
                    int c8 = v & 3;
                    const float* wsrc = w + (size_t)(oblk * O_TILE + oa) * K_RAW
                                          + (ck * KC + c8 * 8) * 9 + tap;
                    bf16x8 val;
#pragma unroll
                    for (int j = 0; j < 8; ++j)
                        val[j] = (wsrc[j * 9] >= 0.0f) ? (__bf16)1.0f : (__bf16)(-1.0f);
                    *(bf16x8*)(&Asf[oa * PITCH + c8 * 8]) = val;
                }
            }
            {
                const int cbase = (ck * KC + cgrp * 16) * HW + offs;
#pragma unroll
                for (int g = 0; g < 2; ++g) {
                    bf16x8 vb;
#pragma unroll
                    for (int j = 0; j < 8; ++j) {
                        float f = valid ? xbase[cbase + (g * 8 + j) * HW] : 0.0f;
                        vb[j] = (__bf16)f;
                    }
                    *(bf16x8*)(&Bsf[p_local * PITCH + cgrp * 16 + g * 8]) = vb;
                }
            }
            __syncthreads();
            bf16x8 bfrag[2];
#pragma unroll
            for (int nt = 0; nt < 2; ++nt)
                bfrag[nt] = *(const bf16x8*)(&Bsf[(pix_wave + nt * 16 + row) * PITCH + quad * 8]);
#pragma unroll
            for (int mt = 0; mt < 8; ++mt) {
                bf16x8 afrag = *(const bf16x8*)(&Asf[(mt * 16 + row) * PITCH + quad * 8]);
#pragma unroll
                for (int nt = 0; nt < 2; ++nt)
                    acc[mt][nt] = __builtin_amdgcn_mfma_f32_16x16x32_bf16(
                        afrag, bfrag[nt], acc[mt][nt], 0, 0, 0);
            }
        }
    }

#pragma unroll
    for (int nt = 0; nt < 2; ++nt) {
        int pix = pblk * PIX_TILE + pix_wave + nt * 16 + row;
        int ni  = pix / HW;
        int phw = pix - ni * HW;
        float* obase = out + (size_t)ni * (O_OUT * HW) + phw;
#pragma unroll
        for (int mt = 0; mt < 8; ++mt) {
            int o0 = oblk * O_TILE + mt * 16 + quad * 4;
#pragma unroll
            for (int r = 0; r < 4; ++r) {
                int o = o0 + r;
                float sb = (bias[o] >= 0.0f) ? 1.0f : -1.0f;
                obase[(size_t)o * HW] = acc[mt][nt][r] + sb;
            }
        }
    }
}

extern "C" void kernel_launch(void* const* d_in, const int* in_sizes, int n_in,
                              void* d_out, int out_size, void* d_ws, size_t ws_size,
                              hipStream_t stream) {
    const float* x    = (const float*)d_in[0];
    const float* w    = (const float*)d_in[1];
    const float* bias = (const float*)d_in[2];
    float* out        = (float*)d_out;

    if (ws_size >= (size_t)WS_NEED) {
        __bf16* xt = (__bf16*)d_ws;
        __bf16* wt = (__bf16*)((char*)d_ws + XT_BYTES);
        xtrans_kernel<<<dim3(58, 8, N_IMG), dim3(256), 0, stream>>>(x, xt);
        wtrans_kernel<<<WT_ELEMS / 256, 256, 0, stream>>>(w, wt);
        bconv2_kernel<<<dim3(N_IMG * 14, 2), dim3(256), 0, stream>>>(xt, wt, bias, out);
    } else if (ws_size >= (size_t)WT_BYTES) {
        __bf16* wt = (__bf16*)d_ws;
        wtrans_kernel<<<WT_ELEMS / 256, 256, 0, stream>>>(w, wt);
        bconv_kernel<true><<<dim3((N_IMG * HW) / PIX_TILE, 2), dim3(256), 0, stream>>>(
            x, w, wt, bias, out);
    } else {
        bconv_kernel<false><<<dim3((N_IMG * HW) / PIX_TILE, 2), dim3(256), 0, stream>>>(
            x, w, (const __bf16*)nullptr, bias, out);
    }
}